// Round 2
// baseline (96.448 us; speedup 1.0000x reference)
//
#include <hip/hip_runtime.h>

typedef __bf16 bf16x8 __attribute__((ext_vector_type(8)));
typedef float f32x4 __attribute__((ext_vector_type(4)));

// Problem constants
#define BB 4
#define CC 64
#define OO 64
#define HH 128
#define WW 128

// ---------------------------------------------------------------------------
// Kernel 1: prepack weights into MFMA A-fragment order, bf16.
// K-permutation: kperm = (i*3+j)*64 + c  -> K-step t = (i*3+j)*2 + ch, ch selects c-half.
// A-frag for (og, t): lane l holds W[o = og*16 + (l&15)][c = (t&1)*32 + (l>>4)*8 + jj], jj=0..7
// Stored contiguously: aw16[(((og*18)+t)*64 + l)*8 + jj]
// ---------------------------------------------------------------------------
__global__ __launch_bounds__(256) void prepack_kernel(
    const float* __restrict__ w, unsigned short* __restrict__ aw)
{
    int gid = blockIdx.x * 256 + threadIdx.x;   // 0..4607  (4 og * 18 t * 64 lanes)
    if (gid >= 4608) return;
    int og  = gid / 1152;
    int rem = gid - og * 1152;
    int t = rem >> 6;
    int l = rem & 63;
    int q = l >> 4;
    int m = l & 15;
    int o  = og * 16 + m;
    int ij = t >> 1;
    int ch = t & 1;
    int i = ij / 3;
    int j = ij - i * 3;
    union { unsigned short u[8]; uint4 v; } pk;
#pragma unroll
    for (int jj = 0; jj < 8; ++jj) {
        int c = ch * 32 + q * 8 + jj;
        float wf = w[((o * CC + c) * 3 + i) * 3 + j];
        __bf16 h = (__bf16)wf;
        pk.u[jj] = __builtin_bit_cast(unsigned short, h);
    }
    ((uint4*)aw)[gid] = pk.v;
}

// ---------------------------------------------------------------------------
// Kernel 2: prescale + transpose:  xs[b][y][x][c] = bf16( in[b][c][y][x] * f(alpha[b][y][x]) )
// channel-innermost so conv staging reads contiguous 16B channel groups.
// ---------------------------------------------------------------------------
__global__ __launch_bounds__(256) void prescale_kernel(
    const float* __restrict__ in, const float* __restrict__ alpha,
    const float* __restrict__ pa, const float* __restrict__ pb, const float* __restrict__ pc,
    unsigned short* __restrict__ xs)
{
    __shared__ float trans[64][65];   // [c][x], +1 pad
    int bid = blockIdx.x;             // (b*128 + y)*2 + xh
    int xh  = bid & 1;
    int by  = bid >> 1;
    int y   = by & 127;
    int b   = by >> 7;
    int x0  = xh * 64;
    int tid = threadIdx.x;

    float A  = *pa, Bc = *pb, Cc = *pc;

    // read phase: coalesced rows of input, scaled by f(alpha)
    int x  = tid & 63;
    int c4 = tid >> 6;                // 0..3
    float av = alpha[(b * HH + y) * WW + x0 + x];
    float f  = (A * av + Bc) * av + Cc;
#pragma unroll
    for (int k = 0; k < 16; ++k) {
        int c = c4 * 16 + k;
        float v = in[((b * CC + c) * HH + y) * WW + x0 + x];
        trans[c][x] = v * f;
    }
    __syncthreads();

    // write phase: channel-contiguous bf16, 32B per thread
    int xw = tid >> 2;
    int cg = tid & 3;
    union { unsigned short u[16]; uint4 v4[2]; } pk;
#pragma unroll
    for (int k = 0; k < 16; ++k) {
        __bf16 h = (__bf16)trans[cg * 16 + k][xw];
        pk.u[k] = __builtin_bit_cast(unsigned short, h);
    }
    uint4* dst = (uint4*)(xs + (((size_t)(b * HH + y) * WW + x0 + xw) * CC + cg * 16));
    dst[0] = pk.v4[0];
    dst[1] = pk.v4[1];
}

// ---------------------------------------------------------------------------
// Kernel 3: conv. One block per (b, y): 64 o  x  128 x outputs.
// 4 waves: wave w -> oh = w&1 (32 o), nh = w>>1 (64 x). 2x4 mfma_f32_16x16x32_bf16 acc.
// LDS tile[r=3][xt=130][c=64 pad 72] bf16: xt covers input x = xt-1 (halo).
// Stride 72 shorts = 36 dwords: b128 bank-quad residue (m+q)%8 is uniform -> balanced.
// __launch_bounds__(256,2): 2 waves/EU target => <=256 VGPR, no spill.
// #pragma unroll 3 on ij: bounds live-range (full unroll hoisted ~36 A-frags -> spills).
// ---------------------------------------------------------------------------
__global__ __launch_bounds__(256, 2) void conv_kernel(
    const unsigned short* __restrict__ xs, const unsigned short* __restrict__ aw,
    const float* __restrict__ bias, float* __restrict__ out)
{
    __shared__ unsigned short tile[3 * 130 * 72];   // 56,160 B

    // XCD swizzle: xcd = bid&7 handles one (b, y-half) slab -> xs row reuse in that XCD's L2
    int n   = blockIdx.x;             // 0..511
    int xcd = n & 7;
    int idx = n >> 3;                 // 0..63
    int b   = xcd >> 1;
    int y   = (xcd & 1) * 64 + idx;
    int tid = threadIdx.x;

    // stage: 3120 16B chunks (r, xt, g)
    for (int s = tid; s < 3120; s += 256) {
        int g  = s & 7;
        int rx = s >> 3;            // 0..389
        int r  = rx / 130;
        int xt = rx - r * 130;
        int yy = y + r - 1;
        int xg = xt - 1;
        uint4 val = make_uint4(0u, 0u, 0u, 0u);
        if ((unsigned)yy < (unsigned)HH && (unsigned)xg < (unsigned)WW)
            val = *(const uint4*)(xs + (((size_t)(b * HH + yy) * WW + xg) * CC + g * 8));
        *(uint4*)(tile + (r * 130 + xt) * 72 + g * 8) = val;
    }
    __syncthreads();

    int wv = tid >> 6;
    int l  = tid & 63;
    int oh = wv & 1;    // o-half: o in [oh*32, oh*32+32)
    int nh = wv >> 1;   // x-half: x in [nh*64, nh*64+64)
    int q  = l >> 4;
    int m  = l & 15;

    f32x4 acc[2][4];
#pragma unroll
    for (int ag = 0; ag < 2; ++ag)
#pragma unroll
        for (int nf = 0; nf < 4; ++nf)
            acc[ag][nf] = (f32x4){0.f, 0.f, 0.f, 0.f};

    // A-frag base for this wave's o-half: og = oh*2 + ag
    const uint4* awv = (const uint4*)aw + (size_t)(oh * 2) * 18 * 64 + l;

#pragma unroll 3
    for (int ij = 0; ij < 9; ++ij) {
        const int i = ij / 3;
        const int j = ij - i * 3;
#pragma unroll
        for (int ch = 0; ch < 2; ++ch) {
            const int t = ij * 2 + ch;
            bf16x8 afrag[2], bfrag[4];
#pragma unroll
            for (int ag = 0; ag < 2; ++ag)
                afrag[ag] = __builtin_bit_cast(bf16x8, awv[(ag * 18 + t) * 64]);
#pragma unroll
            for (int nf = 0; nf < 4; ++nf) {
                int xt = nh * 64 + nf * 16 + m + j;   // input x = xt-1 = xout + j - 1
                bfrag[nf] = __builtin_bit_cast(bf16x8,
                    *(const uint4*)(tile + (i * 130 + xt) * 72 + ch * 32 + q * 8));
            }
#pragma unroll
            for (int ag = 0; ag < 2; ++ag)
#pragma unroll
                for (int nf = 0; nf < 4; ++nf)
                    acc[ag][nf] = __builtin_amdgcn_mfma_f32_16x16x32_bf16(
                        afrag[ag], bfrag[nf], acc[ag][nf], 0, 0, 0);
        }
    }

    // epilogue: D layout (m89): o = q*4 + r, x = lane&15
#pragma unroll
    for (int ag = 0; ag < 2; ++ag) {
#pragma unroll
        for (int r = 0; r < 4; ++r) {
            int o = (oh * 2 + ag) * 16 + q * 4 + r;
            float bv = bias[o];
#pragma unroll
            for (int nf = 0; nf < 4; ++nf) {
                int x = nh * 64 + nf * 16 + m;
                out[((size_t)(b * OO + o) * HH + y) * WW + x] = acc[ag][nf][r] + bv;
            }
        }
    }
}

// ---------------------------------------------------------------------------
extern "C" void kernel_launch(void* const* d_in, const int* in_sizes, int n_in,
                              void* d_out, int out_size, void* d_ws, size_t ws_size,
                              hipStream_t stream) {
    const float* inputs = (const float*)d_in[0];
    const float* alpha  = (const float*)d_in[1];
    const float* weight = (const float*)d_in[2];
    const float* bias   = (const float*)d_in[3];
    const float* pa     = (const float*)d_in[4];
    const float* pb     = (const float*)d_in[5];
    const float* pc     = (const float*)d_in[6];
    float* out = (float*)d_out;

    unsigned short* aw = (unsigned short*)d_ws;                       // 73,728 B
    unsigned short* xs = (unsigned short*)((char*)d_ws + 131072);     // 8,388,608 B

    prepack_kernel<<<18, 256, 0, stream>>>(weight, aw);
    prescale_kernel<<<BB * HH * 2, 256, 0, stream>>>(inputs, alpha, pa, pb, pc, xs);
    conv_kernel<<<BB * HH, 256, 0, stream>>>(xs, aw, bias, out);
}

// Round 3
// 93.272 us; speedup vs baseline: 1.0341x; 1.0341x over previous
//
#include <hip/hip_runtime.h>

typedef __bf16 bf16x8 __attribute__((ext_vector_type(8)));
typedef float f32x4 __attribute__((ext_vector_type(4)));

// Problem constants
#define BB 4
#define CC 64
#define OO 64
#define HH 128
#define WW 128

// ---------------------------------------------------------------------------
// Kernel 1 (merged "prep"): blocks 0..1023 = prescale+transpose, blocks
// 1024..1041 = weight prepack. Merged so prepack's 18 tiny blocks overlap
// with prescale instead of costing a full serialized graph node.
//
// prescale:  xs[b][y][x][c] = bf16( in[b][c][y][x] * f(alpha[b][y][x]) ),
//            channel-innermost so conv staging reads contiguous 16B chunks.
// prepack:   aw16[(((og*18)+t)*64 + l)*8 + jj] = bf16 W[o][c][i][j] in MFMA
//            A-frag order; t = (i*3+j)*2 + ch, c = ch*32 + (l>>4)*8 + jj,
//            o = og*16 + (l&15).
// ---------------------------------------------------------------------------
__global__ __launch_bounds__(256) void prep_kernel(
    const float* __restrict__ in, const float* __restrict__ alpha,
    const float* __restrict__ w,
    const float* __restrict__ pa, const float* __restrict__ pb, const float* __restrict__ pc,
    unsigned short* __restrict__ xs, unsigned short* __restrict__ aw)
{
    __shared__ float trans[64][65];   // [c][x], +1 pad (prescale branch only)
    int tid = threadIdx.x;

    if (blockIdx.x >= 1024) {
        // ---- prepack branch ----
        int gid = (blockIdx.x - 1024) * 256 + tid;   // 0..4607
        if (gid >= 4608) return;
        int og  = gid / 1152;
        int rem = gid - og * 1152;
        int t = rem >> 6;
        int l = rem & 63;
        int q = l >> 4;
        int m = l & 15;
        int o  = og * 16 + m;
        int ij = t >> 1;
        int ch = t & 1;
        int i = ij / 3;
        int j = ij - i * 3;
        union { unsigned short u[8]; uint4 v; } pk;
#pragma unroll
        for (int jj = 0; jj < 8; ++jj) {
            int c = ch * 32 + q * 8 + jj;
            float wf = w[((o * CC + c) * 3 + i) * 3 + j];
            __bf16 h = (__bf16)wf;
            pk.u[jj] = __builtin_bit_cast(unsigned short, h);
        }
        ((uint4*)aw)[gid] = pk.v;
        return;
    }

    // ---- prescale branch ----
    int bid = blockIdx.x;             // (b*128 + y)*2 + xh
    int xh  = bid & 1;
    int by  = bid >> 1;
    int y   = by & 127;
    int b   = by >> 7;
    int x0  = xh * 64;

    float A  = *pa, Bc = *pb, Cc = *pc;

    // read phase: coalesced rows of input, scaled by f(alpha)
    int x  = tid & 63;
    int c4 = tid >> 6;                // 0..3
    float av = alpha[(b * HH + y) * WW + x0 + x];
    float f  = (A * av + Bc) * av + Cc;
#pragma unroll
    for (int k = 0; k < 16; ++k) {
        int c = c4 * 16 + k;
        float v = in[((b * CC + c) * HH + y) * WW + x0 + x];
        trans[c][x] = v * f;
    }
    __syncthreads();

    // write phase: channel-contiguous bf16, 32B per thread
    int xw = tid >> 2;
    int cg = tid & 3;
    union { unsigned short u[16]; uint4 v4[2]; } pk;
#pragma unroll
    for (int k = 0; k < 16; ++k) {
        __bf16 h = (__bf16)trans[cg * 16 + k][xw];
        pk.u[k] = __builtin_bit_cast(unsigned short, h);
    }
    uint4* dst = (uint4*)(xs + (((size_t)(b * HH + y) * WW + x0 + xw) * CC + cg * 16));
    dst[0] = pk.v4[0];
    dst[1] = pk.v4[1];
}

// ---------------------------------------------------------------------------
// Kernel 2: conv (unchanged from round 2 — passed, analytically clean).
// One block per (b, y): 64 o x 128 x outputs. 4 waves; 2x4
// mfma_f32_16x16x32_bf16 acc per wave. LDS tile[3][130][72] shorts: stride
// 36 dwords -> both staging b128 writes and bfrag b128 reads are
// minimum-aliasing (each 8-lane group covers all 32 banks).
// ---------------------------------------------------------------------------
__global__ __launch_bounds__(256, 2) void conv_kernel(
    const unsigned short* __restrict__ xs, const unsigned short* __restrict__ aw,
    const float* __restrict__ bias, float* __restrict__ out)
{
    __shared__ unsigned short tile[3 * 130 * 72];   // 56,160 B

    // XCD swizzle: xcd = bid&7 handles one (b, y-half) slab
    int n   = blockIdx.x;             // 0..511
    int xcd = n & 7;
    int idx = n >> 3;                 // 0..63
    int b   = xcd >> 1;
    int y   = (xcd & 1) * 64 + idx;
    int tid = threadIdx.x;

    // stage: 3120 16B chunks (r, xt, g)
    for (int s = tid; s < 3120; s += 256) {
        int g  = s & 7;
        int rx = s >> 3;            // 0..389
        int r  = rx / 130;
        int xt = rx - r * 130;
        int yy = y + r - 1;
        int xg = xt - 1;
        uint4 val = make_uint4(0u, 0u, 0u, 0u);
        if ((unsigned)yy < (unsigned)HH && (unsigned)xg < (unsigned)WW)
            val = *(const uint4*)(xs + (((size_t)(b * HH + yy) * WW + xg) * CC + g * 8));
        *(uint4*)(tile + (r * 130 + xt) * 72 + g * 8) = val;
    }
    __syncthreads();

    int wv = tid >> 6;
    int l  = tid & 63;
    int oh = wv & 1;    // o-half: o in [oh*32, oh*32+32)
    int nh = wv >> 1;   // x-half: x in [nh*64, nh*64+64)
    int q  = l >> 4;
    int m  = l & 15;

    f32x4 acc[2][4];
#pragma unroll
    for (int ag = 0; ag < 2; ++ag)
#pragma unroll
        for (int nf = 0; nf < 4; ++nf)
            acc[ag][nf] = (f32x4){0.f, 0.f, 0.f, 0.f};

    const uint4* awv = (const uint4*)aw + (size_t)(oh * 2) * 18 * 64 + l;

#pragma unroll 3
    for (int ij = 0; ij < 9; ++ij) {
        const int i = ij / 3;
        const int j = ij - i * 3;
#pragma unroll
        for (int ch = 0; ch < 2; ++ch) {
            const int t = ij * 2 + ch;
            bf16x8 afrag[2], bfrag[4];
#pragma unroll
            for (int ag = 0; ag < 2; ++ag)
                afrag[ag] = __builtin_bit_cast(bf16x8, awv[(ag * 18 + t) * 64]);
#pragma unroll
            for (int nf = 0; nf < 4; ++nf) {
                int xt = nh * 64 + nf * 16 + m + j;   // input x = xt-1 = xout + j - 1
                bfrag[nf] = __builtin_bit_cast(bf16x8,
                    *(const uint4*)(tile + (i * 130 + xt) * 72 + ch * 32 + q * 8));
            }
#pragma unroll
            for (int ag = 0; ag < 2; ++ag)
#pragma unroll
                for (int nf = 0; nf < 4; ++nf)
                    acc[ag][nf] = __builtin_amdgcn_mfma_f32_16x16x32_bf16(
                        afrag[ag], bfrag[nf], acc[ag][nf], 0, 0, 0);
        }
    }

    // epilogue: D layout (m89): o = q*4 + r, x = lane&15
#pragma unroll
    for (int ag = 0; ag < 2; ++ag) {
#pragma unroll
        for (int r = 0; r < 4; ++r) {
            int o = (oh * 2 + ag) * 16 + q * 4 + r;
            float bv = bias[o];
#pragma unroll
            for (int nf = 0; nf < 4; ++nf) {
                int x = nh * 64 + nf * 16 + m;
                out[((size_t)(b * OO + o) * HH + y) * WW + x] = acc[ag][nf][r] + bv;
            }
        }
    }
}

// ---------------------------------------------------------------------------
extern "C" void kernel_launch(void* const* d_in, const int* in_sizes, int n_in,
                              void* d_out, int out_size, void* d_ws, size_t ws_size,
                              hipStream_t stream) {
    const float* inputs = (const float*)d_in[0];
    const float* alpha  = (const float*)d_in[1];
    const float* weight = (const float*)d_in[2];
    const float* bias   = (const float*)d_in[3];
    const float* pa     = (const float*)d_in[4];
    const float* pb     = (const float*)d_in[5];
    const float* pc     = (const float*)d_in[6];
    float* out = (float*)d_out;

    unsigned short* aw = (unsigned short*)d_ws;                       // 73,728 B
    unsigned short* xs = (unsigned short*)((char*)d_ws + 131072);     // 8,388,608 B

    prep_kernel<<<1024 + 18, 256, 0, stream>>>(inputs, alpha, weight, pa, pb, pc, xs, aw);
    conv_kernel<<<BB * HH, 256, 0, stream>>>(xs, aw, bias, out);
}